// Round 2
// baseline (402.204 us; speedup 1.0000x reference)
//
#include <hip/hip_runtime.h>

// AlignmentMatrix: out[b,i,j] = sum_d body[b,i,d]*w3[d]*pun[b,j,d]
//                             + dot(body[b,i,:],w1) + dot(pun[b,j,:],w2)
// B=64, L=1024, D=128, fp32 in/out.
//
// R4: (1) double-buffered global_load_lds with counted vmcnt(4) + raw
// s_barrier (T3/T4 pattern) -- next chunk's loads stay in flight across the
// barrier instead of the __syncthreads vmcnt(0) drain that killed R3.
// (2) swapped MFMA operands (A=pun, B=body) so each lane's 4 acc values are
// consecutive j -> float4 stores (8 per thread instead of 32 dword stores).
// prep pass (bf16 hi/lo split, w3 folded into body) unchanged from R3.

#define LSEQ 1024
#define H2K  128

// ws layout:
//   ws[0      .. 65536)   s_body (fp32)
//   ws[65536  .. 131072)  s_pun  (fp32)
//   shorts at base=(short*)(ws+131072):
//     [0        ..  8388608)  body*w3  bf16 hi
//     [8388608  .. 16777216)  body*w3  bf16 lo
//     [16777216 .. 25165824)  pun      bf16 hi
//     [25165824 .. 33554432)  pun      bf16 lo

typedef __attribute__((ext_vector_type(8))) short bfrag;
typedef __attribute__((ext_vector_type(4))) float f32x4;

__device__ __forceinline__ short f2bf(float x) {
    unsigned u = __float_as_uint(x);
    unsigned r = (u + 0x7fff + ((u >> 16) & 1)) >> 16;   // RNE
    return (short)r;
}
__device__ __forceinline__ float bf2f(short s) {
    return __uint_as_float(((unsigned)(unsigned short)s) << 16);
}

__device__ __forceinline__ void ld16(void* lds, const void* g) {
    __builtin_amdgcn_global_load_lds(
        (const __attribute__((address_space(1))) void*)g,
        (__attribute__((address_space(3))) void*)lds, 16, 0, 0);
}

// --- pre-pass: one wave per row. fp32 rank-1 dot + bf16 hi/lo split write.
__global__ __launch_bounds__(256) void prep_kernel(
    const float* __restrict__ body, const float* __restrict__ pun,
    const float* __restrict__ w_u, float* __restrict__ ws)
{
    const int flag = blockIdx.y;                   // 0=body, 1=pun
    const int lane = threadIdx.x & 63;
    const int wv   = threadIdx.x >> 6;
    const size_t row = (size_t)blockIdx.x * 4 + wv;        // [0, B*LSEQ)

    const float* src = (flag ? pun : body) + row * H2K;
    const float2 v  = *(const float2*)(src + lane * 2);
    const float2 wm = *(const float2*)(w_u + flag * H2K + lane * 2);

    float p = v.x * wm.x + v.y * wm.y;
    p += __shfl_xor(p, 32);
    p += __shfl_xor(p, 16);
    p += __shfl_xor(p, 8);
    p += __shfl_xor(p, 4);
    p += __shfl_xor(p, 2);
    p += __shfl_xor(p, 1);
    if (lane == 0) ws[(size_t)flag * 65536 + row] = p;

    float cx = v.x, cy = v.y;
    if (!flag) {
        const float2 w3v = *(const float2*)(w_u + 2 * H2K + lane * 2);
        cx *= w3v.x; cy *= w3v.y;
    }
    const short h0 = f2bf(cx), h1 = f2bf(cy);
    const short l0 = f2bf(cx - bf2f(h0)), l1 = f2bf(cy - bf2f(h1));

    short* hb = (short*)(ws + 131072) + (size_t)flag * 16777216 + row * H2K + lane * 2;
    *(unsigned*)hb =
        ((unsigned)(unsigned short)h0) | ((unsigned)(unsigned short)h1 << 16);
    *(unsigned*)(hb + 8388608) =
        ((unsigned)(unsigned short)l0) | ((unsigned)(unsigned short)l1 << 16);
}

// --- main kernel: 128x128 tile / 512 threads, K chunked 4x32, dbuf LDS.
__global__ __launch_bounds__(512, 4) void align_mfma(
    const float* __restrict__ ws, float* __restrict__ out)
{
    // C = body (MFMA B operand), P = pun (MFMA A operand). 64 KB total.
    __shared__ __align__(16) short Ch[2][4096], Cl[2][4096];
    __shared__ __align__(16) short Ph[2][4096], Pl[2][4096];

    const int bb = blockIdx.z;
    const int ti = blockIdx.y * 128;   // body rows (output rows)
    const int tj = blockIdx.x * 128;   // pun rows  (output cols)
    const int t    = threadIdx.x;
    const int lane = t & 63;
    const int w    = t >> 6;           // wave id 0..7

    // Staging: thread t owns fragment (tile = w, lane): row = w*16+(lane&15),
    // k8 = lane>>4. LDS dest byte = t*16 (wave-uniform base + lane*16). ✓
    const int srow = w * 16 + (lane & 15);
    const int k8   = lane >> 4;
    const short* base = (const short*)(ws + 131072);
    const size_t crow = (size_t)(bb * LSEQ + ti + srow) * H2K + k8 * 8;
    const size_t prow = (size_t)(bb * LSEQ + tj + srow) * H2K + k8 * 8;
    const short* gCh = base + crow;
    const short* gCl = base + 8388608 + crow;
    const short* gPh = base + 16777216 + prow;
    const short* gPl = base + 25165824 + prow;

    const int mt0 = (w >> 1) * 2;      // pun tiles (A operand): 2 per wave
    const int nt0 = (w & 1) * 4;       // body tiles (B operand): 4 per wave
    f32x4 acc[2][4] = {};

    // prologue: stage chunk 0 into buf 0
    ld16(&Ch[0][t * 8], gCh);
    ld16(&Cl[0][t * 8], gCl);
    ld16(&Ph[0][t * 8], gPh);
    ld16(&Pl[0][t * 8], gPl);

#pragma unroll
    for (int kt = 0; kt < 4; ++kt) {
        const int cur = kt & 1, nxt = cur ^ 1;

        // stage chunk kt+1 (stays in flight across the barrier)
        if (kt < 3) {
            ld16(&Ch[nxt][t * 8], gCh + (kt + 1) * 32);
            ld16(&Cl[nxt][t * 8], gCl + (kt + 1) * 32);
            ld16(&Ph[nxt][t * 8], gPh + (kt + 1) * 32);
            ld16(&Pl[nxt][t * 8], gPl + (kt + 1) * 32);
        }
        __builtin_amdgcn_sched_barrier(0);
        if (kt < 3) asm volatile("s_waitcnt vmcnt(4)" ::: "memory");
        else        asm volatile("s_waitcnt vmcnt(0)" ::: "memory");
        __builtin_amdgcn_s_barrier();   // all waves' chunk-kt loads landed

        // compute chunk kt: 24 MFMAs
        bfrag ph[2], pl[2], ch[4], cl[4];
#pragma unroll
        for (int i = 0; i < 2; ++i) {
            ph[i] = *(const bfrag*)&Ph[cur][((mt0 + i) * 64 + lane) * 8];
            pl[i] = *(const bfrag*)&Pl[cur][((mt0 + i) * 64 + lane) * 8];
        }
#pragma unroll
        for (int j = 0; j < 4; ++j) {
            ch[j] = *(const bfrag*)&Ch[cur][((nt0 + j) * 64 + lane) * 8];
            cl[j] = *(const bfrag*)&Cl[cur][((nt0 + j) * 64 + lane) * 8];
        }
#pragma unroll
        for (int i = 0; i < 2; ++i)
#pragma unroll
            for (int j = 0; j < 4; ++j) {
                acc[i][j] = __builtin_amdgcn_mfma_f32_16x16x32_bf16(ph[i], ch[j], acc[i][j], 0, 0, 0);
                acc[i][j] = __builtin_amdgcn_mfma_f32_16x16x32_bf16(ph[i], cl[j], acc[i][j], 0, 0, 0);
                acc[i][j] = __builtin_amdgcn_mfma_f32_16x16x32_bf16(pl[i], ch[j], acc[i][j], 0, 0, 0);
            }

        if (kt < 3) __builtin_amdgcn_s_barrier();  // protect buf before restage
        __builtin_amdgcn_sched_barrier(0);
    }

    // ---- epilogue: swapped layout -> float4 stores along j ----
    // D mapping: col=lane&15 -> body row i (B operand); reg v + (lane>>4)*4 -> pun col j.
    const float* sbp = ws + (size_t)bb * LSEQ;            // s_body, by i
    const float* spp = ws + 65536 + (size_t)bb * LSEQ;    // s_pun,  by j
    const int q = lane >> 4, ln = lane & 15;
#pragma unroll
    for (int mi = 0; mi < 2; ++mi) {                      // pun tiles
        const int j0 = tj + (mt0 + mi) * 16 + q * 4;
        const float4 spv = *(const float4*)(spp + j0);
#pragma unroll
        for (int ni = 0; ni < 4; ++ni) {                  // body tiles
            const int row = ti + (nt0 + ni) * 16 + ln;
            const float sb = sbp[row];
            const f32x4 a = acc[mi][ni];
            float4 r = { a[0] + sb + spv.x, a[1] + sb + spv.y,
                         a[2] + sb + spv.z, a[3] + sb + spv.w };
            *(float4*)&out[((size_t)bb * LSEQ + row) * LSEQ + j0] = r;
        }
    }
}

extern "C" void kernel_launch(void* const* d_in, const int* in_sizes, int n_in,
                              void* d_out, int out_size, void* d_ws, size_t ws_size,
                              hipStream_t stream) {
    const float* body = (const float*)d_in[1];
    const float* pun  = (const float*)d_in[2];
    const float* w_u  = (const float*)d_in[3];
    float* out = (float*)d_out;
    float* ws  = (float*)d_ws;
    const int B = in_sizes[1] / (LSEQ * H2K);

    dim3 g1((B * LSEQ) / 4, 2, 1);
    prep_kernel<<<g1, 256, 0, stream>>>(body, pun, w_u, ws);

    dim3 g2(LSEQ / 128, LSEQ / 128, B);
    align_mfma<<<g2, 512, 0, stream>>>(ws, out);
}